// Round 11
// baseline (9126.751 us; speedup 1.0000x reference)
//
#include <hip/hip_runtime.h>
#include <math.h>
#include <float.h>

#define BN   2
#define NPTS 16384
#define MPTS 4096
#define KGN  32
#define CIN  64
#define CLN  64

// ---------- exact fp32 helpers (no FMA contraction; must match np fp32) ----------
__device__ __forceinline__ float exadd(float a, float b) {
#pragma clang fp contract(off)
    float r = a + b; return r;
}
__device__ __forceinline__ float exsub(float a, float b) {
#pragma clang fp contract(off)
    float r = a - b; return r;
}
__device__ __forceinline__ float exmul(float a, float b) {
#pragma clang fp contract(off)
    float r = a * b; return r;
}

// ---------- packed fp32 via NATIVE vector types (no inline asm).
// ISel lowers <2 x float> add/sub/mul to v_pk_add_f32 / v_pk_mul_f32
// (VOP3P, gfx90a+): per-component semantics IDENTICAL to the scalar
// v_add/v_sub/v_mul (IEEE fp32). contract(off) forbids FMA formation,
// so the value chain matches the scalar reference bit-for-bit.
typedef float f32x2 __attribute__((ext_vector_type(2)));

__device__ __forceinline__ f32x2 vsub2(f32x2 a, f32x2 b) {
#pragma clang fp contract(off)
    f32x2 r = a - b; return r;
}
__device__ __forceinline__ f32x2 vmul2(f32x2 a, f32x2 b) {
#pragma clang fp contract(off)
    f32x2 r = a * b; return r;
}
__device__ __forceinline__ f32x2 vadd2(f32x2 a, f32x2 b) {
#pragma clang fp contract(off)
    f32x2 r = a + b; return r;
}

__device__ __forceinline__ float wave_sum64(float v) {
#pragma unroll
    for (int off = 1; off < 64; off <<= 1) v += __shfl_xor(v, off);
    return v;
}

// =====================================================================
// K0: pack points as float4(x, y, z, ||p||^2) once. sb order matches
// jnp.sum(b*b,-1): ((x*x + y*y) + z*z), contract off. Values verbatim.
// =====================================================================
__global__ __launch_bounds__(256) void prep_kernel(const float* __restrict__ xyz,
                                                   float4* __restrict__ pts4) {
    const int i = blockIdx.x * 256 + threadIdx.x;   // 0 .. BN*NPTS-1
    const float x = xyz[3 * i + 0];
    const float y = xyz[3 * i + 1];
    const float z = xyz[3 * i + 2];
    const float sb = exadd(exadd(exmul(x, x), exmul(y, y)), exmul(z, z));
    pts4[i] = make_float4(x, y, z, sb);
}

// =====================================================================
// K1: FPS — R13: R10 packed update + SERIAL-CHAIN SURGERY.
// R10 falsified the VALU-bound theory: packing cut VALUBusy/active-CU
// 84%->57% but time was flat => the binding constraint is the serial
// latency chain (reduce deps + 2 barriers + LDS reads + the
// readfirstlane+s_load centroid reload from L2 ~250-350 cyc).
// This round removes the two largest links:
//  1. NO centroid global load: post-B1, each candidate wave's FIRST
//     candidate lane (the wave's min-index candidate: lane t owns
//     t*16..t*16+15, so lower lane => lower index; in-lane sel is
//     minimal) extends its scan to capture (wx,wy,wz) and writes ONE
//     float4 to scoordw[m&1][wid] BEFORE B2. Post-B2 every thread
//     broadcast-reads scoordw[m&1][widx>>10] (~120 cyc ds_read_b128
//     replaces ~250-350 cyc readfirstlane+s_load).
//     Race-freedom (ping-pong, same as swidx): write(m) is pre-B2(m);
//     reads(m) are post-B2(m) and precede B1(m+1); the next write to
//     the same slot set is at iter m+2, after B1(m+2) > B1(m+1).
//     The winner's wave wrote its slot THIS iteration (the block
//     winner is its own wave's first candidate lane). Stale slots of
//     non-candidate waves are never selected.
//  2. ONE atomicMin per candidate WAVE (firstlane), not per candidate
//     thread — any other candidate lane t' > t has index t'*16+sel' >
//     t*16+15 >= firstlane's index, so dropping them never changes the
//     block min.
// Value chain verbatim (update/fminf/tie-break bit-identical; coords
// are exact register copies). First-occurrence argmax preserved:
// in-thread descending scan -> smallest i; per-wave firstlane ->
// wave-min index; atomicMin across waves -> block-min index.
// swidx ping-pong reset ordering (R1-proven): reset of slot (m+1)&1
// sits between B1(m) and B2(m); readers finished before B1(m); next
// writers start after B1(m+1) > B2(m) > reset. No race.
// =====================================================================
__global__ __launch_bounds__(1024, 4) void fps_kernel(const float4* __restrict__ P4,
                                                      int* __restrict__ out_idx) {
    const int b = blockIdx.x;
    const int t = threadIdx.x;
    const int lane = t & 63;
    const int wid  = t >> 6;
    const float4* P = P4 + (size_t)b * NPTS;

    // ---- load 16 points (8 pairs): coords packed f32x2, dist scalar ----
#define FPS_LOAD(p, i0, i1) \
    float4 a##i0 = P[t * 16 + i0]; \
    float4 a##i1 = P[t * 16 + i1]; \
    f32x2 px##p = {a##i0.x, a##i1.x}; \
    f32x2 py##p = {a##i0.y, a##i1.y}; \
    f32x2 pz##p = {a##i0.z, a##i1.z}; \
    float dd##i0 = 1e10f, dd##i1 = 1e10f;
    FPS_LOAD(0, 0, 1)   FPS_LOAD(1, 2, 3)
    FPS_LOAD(2, 4, 5)   FPS_LOAD(3, 6, 7)
    FPS_LOAD(4, 8, 9)   FPS_LOAD(5, 10, 11)
    FPS_LOAD(6, 12, 13) FPS_LOAD(7, 14, 15)
#undef FPS_LOAD

    __shared__ float  smax[16];
    __shared__ int    swidx[2];
    __shared__ float4 scoordw[2][16];

    if (t == 0) { swidx[0] = 0x7FFFFFFF; swidx[1] = 0x7FFFFFFF; }
    __syncthreads();

    int cidx = 0;                      // centroid index == out_idx[m]
    // centroid 0 coords: uniform load once (reference far starts at 0)
    float cx, cy, cz;
    {
        const float4 C0 = P[0];
        cx = C0.x; cy = C0.y; cz = C0.z;
    }

    for (int m = 0; m < MPTS; ++m) {
        if (t == 0) out_idx[b * MPTS + m] = cidx;   // fire-and-forget store

        const f32x2 cx2 = {cx, cx};
        const f32x2 cy2 = {cy, cy};
        const f32x2 cz2 = {cz, cz};

        float lmax = -1.0f;
#define FPS_UPD(p, i0, i1) { \
        f32x2 dx = vsub2(px##p, cx2); \
        f32x2 dy = vsub2(py##p, cy2); \
        f32x2 dz = vsub2(pz##p, cz2); \
        f32x2 d  = vadd2(vadd2(vmul2(dx, dx), vmul2(dy, dy)), vmul2(dz, dz)); \
        dd##i0 = fminf(dd##i0, d.x); \
        dd##i1 = fminf(dd##i1, d.y); \
        lmax = fmaxf(fmaxf(lmax, dd##i0), dd##i1); }
        FPS_UPD(0, 0, 1)   FPS_UPD(1, 2, 3)
        FPS_UPD(2, 4, 5)   FPS_UPD(3, 6, 7)
        FPS_UPD(4, 8, 9)   FPS_UPD(5, 10, 11)
        FPS_UPD(6, 12, 13) FPS_UPD(7, 14, 15)
#undef FPS_UPD

        // wave-level f32 max
        float wmax = lmax;
#pragma unroll
        for (int off = 1; off < 64; off <<= 1) wmax = fmaxf(wmax, __shfl_xor(wmax, off));
        if (lane == 0) smax[wid] = wmax;

        __syncthreads();                               // B1

        // reset the slot used NEXT iteration (ordering: see header proof)
        if (t == 0) swidx[(m + 1) & 1] = 0x7FFFFFFF;

        // block max — replicated parallel reduce, every thread ends with bm
        float bm = smax[t & 15];
#pragma unroll
        for (int off = 1; off < 16; off <<= 1) bm = fmaxf(bm, __shfl_xor(bm, off));

        // per-wave: FIRST candidate lane publishes wave-min index + coords
        const unsigned long long cand = __ballot(lmax == bm);
        if (cand != 0ull && lane == __ffsll(cand) - 1) {
            int sel = 0;
            float wx = 0.f, wy = 0.f, wz = 0.f;
            // descending scan (pair i1 before i0): last assignment wins
            // -> smallest matching i; also captures that point's coords.
#define FPS_SCAN(p, i0, i1) \
            if (dd##i1 == bm) { sel = i1; wx = px##p.y; wy = py##p.y; wz = pz##p.y; } \
            if (dd##i0 == bm) { sel = i0; wx = px##p.x; wy = py##p.x; wz = pz##p.x; }
            FPS_SCAN(7, 14, 15) FPS_SCAN(6, 12, 13)
            FPS_SCAN(5, 10, 11) FPS_SCAN(4, 8, 9)
            FPS_SCAN(3, 6, 7)   FPS_SCAN(2, 4, 5)
            FPS_SCAN(1, 2, 3)   FPS_SCAN(0, 0, 1)
#undef FPS_SCAN
            atomicMin(&swidx[m & 1], t * 16 + sel);
            scoordw[m & 1][wid] = make_float4(wx, wy, wz, 0.0f);
        }

        __syncthreads();                               // B2

        const int widx = swidx[m & 1];
        const float4 C = scoordw[m & 1][widx >> 10];   // broadcast ds_read_b128
        cx = C.x; cy = C.y; cz = C.z;
        cidx = widx;
    }
}

// =====================================================================
// K2: exact 32-NN, wave per centroid, NO per-lane arrays.
// Wave-wide sorted top-32 lives in ONE (key,idx) register pair per
// lane (lanes 0..31, ascending (key,idx) lex). Candidates found via
// ballot; each inserted exactly: p = popc(ballot(lex-less)), shift
// lanes >= p up by one, lane p takes the candidate.
// Exactness: selection by (key,idx) lex = lax.top_k stable set; insert
// order irrelevant (final content = top-32 of union). Keys use the
// exact chain: d2 = (sa+sb) - 2*dot, key = fmaxf(d2,0).
// Radius pre-filter sqrtf(dk)<=0.8f is set-equivalent: the radius set
// is down-closed in key order, so top32(all) ∩ radius == top32(radius).
// Sentinels (FLT_MAX, idx 0) fail the mask in mlp; idx 0 safe gather.
// =====================================================================
__global__ __launch_bounds__(256) void knn_kernel(const float4* __restrict__ pts4,
                                                  const int* __restrict__ fps_idx,
                                                  float* __restrict__ newxyz,
                                                  int* __restrict__ nn_idx,
                                                  float* __restrict__ nn_key) {
    const int lane = threadIdx.x & 63;
    const int g    = blockIdx.x * 4 + (threadIdx.x >> 6);   // centroid 0..8191
    const int b    = g >> 12;
    const float4* P = pts4 + (size_t)b * NPTS;

    const int far = fps_idx[g];
    const float4 C = P[far];
    if (lane == 0) {
        newxyz[g * 3 + 0] = C.x;
        newxyz[g * 3 + 1] = C.y;
        newxyz[g * 3 + 2] = C.z;
    }
    const float sa = C.w;

    float skey = FLT_MAX;   // lanes 0..31: sorted entries; lanes 32..63: inert
    int   sidx = 0;

    for (int it = 0; it < NPTS / 64; ++it) {
        const int j = it * 64 + lane;
        const float4 Q = P[j];
        const float dot = exadd(exadd(exmul(C.x, Q.x), exmul(C.y, Q.y)), exmul(C.z, Q.z));
        const float d2  = exsub(exadd(sa, Q.w), exadd(dot, dot));
        const float dk  = fmaxf(d2, 0.0f);
        // current 32nd-best (tau) from lane 31 — stale within the iteration is
        // fine: the insert itself recomputes the exact position.
        const float tk = __shfl(skey, 31);
        const int   ti = __shfl(sidx, 31);
        const bool pass = (sqrtf(dk) <= 0.8f) &&
                          ((dk < tk) || (dk == tk && j < ti));
        unsigned long long mask = __ballot(pass);
        while (mask) {
            const int src = __ffsll(mask) - 1;
            mask &= mask - 1;
            const float ck = __shfl(dk, src);
            const int   cj = it * 64 + src;
            const bool less = (skey < ck) || (skey == ck && sidx < cj);
            const int p = __popcll(__ballot(less));   // wave-uniform rank
            if (p < 32) {                              // wave-uniform branch
                const float upk = __shfl_up(skey, 1);
                const int   upi = __shfl_up(sidx, 1);
                if (lane < 32) {
                    if (lane == p)     { skey = ck;  sidx = cj; }
                    else if (lane > p) { skey = upk; sidx = upi; }
                }
            }
        }
    }
    if (lane < KGN) {
        nn_idx[(size_t)g * KGN + lane] = sidx;
        nn_key[(size_t)g * KGN + lane] = skey;
    }
}

// =====================================================================
// K3: shared MLP 3->32->32->64 (+BN affine +ReLU), radius mask via
// sqrtf(nn_key) <= 0.8, max over 32 neighbors.
// =====================================================================
__global__ __attribute__((amdgpu_waves_per_eu(4, 4)))
__launch_bounds__(256) void mlp_kernel(const float* __restrict__ xyz,
                                       const float* __restrict__ w1, const float* __restrict__ s1, const float* __restrict__ b1,
                                       const float* __restrict__ w2, const float* __restrict__ s2, const float* __restrict__ b2,
                                       const float* __restrict__ w3, const float* __restrict__ s3, const float* __restrict__ b3,
                                       const float* __restrict__ newxyz,
                                       const int* __restrict__ nn_idx,
                                       const float* __restrict__ nn_key,
                                       float* __restrict__ FLout) {
    __shared__ float W1[96], S1[32], B1[32];
    __shared__ float W2[1024], S2[32], B2[32];
    __shared__ float W3[2048], S3[64], B3[64];
    const int tid = threadIdx.x;
    for (int i = tid; i < 96; i += 256)   W1[i] = w1[i];
    for (int i = tid; i < 32; i += 256) { S1[i] = s1[i]; B1[i] = b1[i]; S2[i] = s2[i]; B2[i] = b2[i]; }
    for (int i = tid; i < 1024; i += 256) W2[i] = w2[i];
    for (int i = tid; i < 2048; i += 256) W3[i] = w3[i];
    for (int i = tid; i < 64; i += 256) { S3[i] = s3[i]; B3[i] = b3[i]; }
    __syncthreads();

    const int n  = tid & 31;
    const int g  = blockIdx.x * 8 + (tid >> 5);   // centroid 0..8191
    const int b  = g >> 12;
    const size_t base = (size_t)g * KGN + n;
    const int   nj = nn_idx[base];
    const float nk = nn_key[base];

    const float* X = xyz + (size_t)b * NPTS * 3;
    const float gx = X[nj * 3 + 0] - newxyz[g * 3 + 0];
    const float gy = X[nj * 3 + 1] - newxyz[g * 3 + 1];
    const float gz = X[nj * 3 + 2] - newxyz[g * 3 + 2];

    float h1[32];
#pragma unroll
    for (int o = 0; o < 32; ++o) {
        float a = gx * W1[o * 3 + 0] + gy * W1[o * 3 + 1] + gz * W1[o * 3 + 2];
        h1[o] = fmaxf(a * S1[o] + B1[o], 0.0f);
    }
    float h2[32];
#pragma unroll
    for (int o = 0; o < 32; ++o) {
        float a = 0.0f;
#pragma unroll
        for (int k = 0; k < 32; ++k) a += h1[k] * W2[o * 32 + k];
        h2[o] = fmaxf(a * S2[o] + B2[o], 0.0f);
    }
    const bool valid = (sqrtf(nk) <= 0.8f);   // exact mask (sentinel FLT_MAX -> false)

    for (int o = 0; o < 64; ++o) {
        float a = 0.0f;
#pragma unroll
        for (int k = 0; k < 32; ++k) a += h2[k] * W3[o * 32 + k];
        float v = fmaxf(a * S3[o] + B3[o], 0.0f);
        v = valid ? v : -INFINITY;
#pragma unroll
        for (int off = 1; off < 32; off <<= 1) v = fmaxf(v, __shfl_xor(v, off));
        if (n == (o & 31)) FLout[(size_t)g * CLN + o] = v;
    }
}

// =====================================================================
// K4: DAM fusion. Wave per centroid, lane = channel.
// LDS-transposed 64x64 weights for conflict-free per-lane reads.
// =====================================================================
__global__ __launch_bounds__(256) void fuse_kernel(const float* __restrict__ pts_cam,
                                                   const float* __restrict__ FIn,
                                                   const float* __restrict__ tw1, const float* __restrict__ tb1,
                                                   const float* __restrict__ tw2, const float* __restrict__ tb2,
                                                   const float* __restrict__ tw3, const float* __restrict__ tb3,
                                                   const float* __restrict__ gw_raw, const float* __restrict__ gb_raw,
                                                   const float* __restrict__ gw_img, const float* __restrict__ gb_img,
                                                   const float* __restrict__ gw_lid, const float* __restrict__ gb_lid,
                                                   const float* __restrict__ uw, const float* __restrict__ ub,
                                                   const float* __restrict__ vw, const float* __restrict__ vb,
                                                   const int* __restrict__ fps_idx,
                                                   const float* __restrict__ newxyz,
                                                   const float* __restrict__ FLin,
                                                   float* __restrict__ out) {
    __shared__ float WIm[4096], WLi[4096], WT2[4096];
    const int tid = threadIdx.x;
    for (int i = tid; i < 4096; i += 256) {
        int c = i >> 6, k = i & 63;          // weight[c][k] -> transposed [k][c]
        WIm[k * 64 + c] = gw_img[i];
        WLi[k * 64 + c] = gw_lid[i];
        WT2[k * 64 + c] = tw2[i];
    }
    __syncthreads();

    const int lane = tid & 63;
    const int g    = blockIdx.x * 4 + (tid >> 6);   // centroid 0..8191
    const int b    = g >> 12;
    const int m    = g & (MPTS - 1);
    const int far  = fps_idx[g];

    const float fi_in = FIn[((size_t)(b * CIN + lane)) * NPTS + far];
    const float fl_in = FLin[(size_t)g * CLN + lane];
    const float nx = newxyz[g * 3 + 0], ny = newxyz[g * 3 + 1], nz = newxyz[g * 3 + 2];

    float fr = fmaxf(nx * gw_raw[lane * 3 + 0] + ny * gw_raw[lane * 3 + 1] +
                     nz * gw_raw[lane * 3 + 2] + gb_raw[lane], 0.0f);

    float ai = gb_img[lane], al = gb_lid[lane];
#pragma unroll 8
    for (int k = 0; k < 64; ++k) {
        float vi = __shfl(fi_in, k);
        float vl = __shfl(fl_in, k);
        ai += vi * WIm[k * 64 + lane];
        al += vl * WLi[k * 64 + lane];
    }
    const float s = tanhf(fr + fmaxf(ai, 0.0f) + fmaxf(al, 0.0f));

    // AdaptiveThresholdNet on constant density
    const float dens = (float)(64.0 / (4.0 / 3.0 * 3.14159 * 1.0));
    float t1 = fmaxf(dens * tw1[lane] + tb1[lane], 0.0f);
    float a2 = tb2[lane];
#pragma unroll 8
    for (int k = 0; k < 64; ++k) a2 += __shfl(t1, k) * WT2[k * 64 + lane];
    float t2 = fmaxf(a2, 0.0f);
    float a3 = wave_sum64(t2 * tw3[lane]) + tb3[0];
    float thr = 20.0f + 40.0f * (1.0f / (1.0f + expf(-a3)));

    float aI = wave_sum64(s * uw[lane]) + ub[0];
    float aL = wave_sum64(s * vw[lane]) + vb[0];
    float wIv = 1.0f / (1.0f + expf(-aI));
    float wLv = 1.0f / (1.0f + expf(-aL));

    const float z = pts_cam[((size_t)b * NPTS + far) * 3 + 2];
    const bool near = (z <= thr);

    const size_t o1 = ((size_t)(b * 128 + lane)) * MPTS + m;
    out[o1]                       = near ? fl_in        : fi_in;
    out[o1 + (size_t)64 * MPTS]   = near ? fi_in * wIv  : fl_in * wLv;
}

// =====================================================================
extern "C" void kernel_launch(void* const* d_in, const int* in_sizes, int n_in,
                              void* d_out, int out_size, void* d_ws, size_t ws_size,
                              hipStream_t stream) {
    const float* xyz     = (const float*)d_in[0];
    const float* pts_cam = (const float*)d_in[1];
    const float* FI      = (const float*)d_in[2];
    const float* w1 = (const float*)d_in[3];
    const float* s1 = (const float*)d_in[4];
    const float* b1 = (const float*)d_in[5];
    const float* w2 = (const float*)d_in[6];
    const float* s2 = (const float*)d_in[7];
    const float* b2 = (const float*)d_in[8];
    const float* w3 = (const float*)d_in[9];
    const float* s3 = (const float*)d_in[10];
    const float* b3 = (const float*)d_in[11];
    const float* tw1 = (const float*)d_in[12];
    const float* tb1 = (const float*)d_in[13];
    const float* tw2 = (const float*)d_in[14];
    const float* tb2 = (const float*)d_in[15];
    const float* tw3 = (const float*)d_in[16];
    const float* tb3 = (const float*)d_in[17];
    const float* gw_raw = (const float*)d_in[18];
    const float* gb_raw = (const float*)d_in[19];
    const float* gw_img = (const float*)d_in[20];
    const float* gb_img = (const float*)d_in[21];
    const float* gw_lid = (const float*)d_in[22];
    const float* gb_lid = (const float*)d_in[23];
    const float* uw = (const float*)d_in[24];
    const float* ub = (const float*)d_in[25];
    const float* vw = (const float*)d_in[26];
    const float* vb = (const float*)d_in[27];
    float* out = (float*)d_out;

    // workspace layout (bytes) — total 4,325,376.
    // pts4 is dead after knn; FL (written by mlp, later) aliases its region.
    char* ws = (char*)d_ws;
    int*    ws_idx    = (int*)   (ws + 0);         // 8192 ints    (32 KB)
    float*  ws_newxyz = (float*) (ws + 32768);     // 24576 f      (96 KB)  -> 131072
    float4* ws_pts4   = (float4*)(ws + 131072);    // 32768 float4 (512 KB) -> 655360 [dead after knn]
    float*  ws_FL     = (float*) (ws + 131072);    // 524288 f     (2 MB)   -> 2228224 [aliases pts4]
    int*    ws_nnidx  = (int*)   (ws + 2228224);   // 262144 ints  (1 MB)   -> 3276800
    float*  ws_nnkey  = (float*) (ws + 3276800);   // 262144 f     (1 MB)   -> 4325376
    (void)ws_size; (void)in_sizes; (void)n_in; (void)out_size;

    prep_kernel<<<(BN * NPTS) / 256, 256, 0, stream>>>(xyz, ws_pts4);
    fps_kernel<<<BN, 1024, 0, stream>>>(ws_pts4, ws_idx);
    knn_kernel<<<2048, 256, 0, stream>>>(ws_pts4, ws_idx, ws_newxyz, ws_nnidx, ws_nnkey);
    mlp_kernel<<<1024, 256, 0, stream>>>(xyz, w1, s1, b1, w2, s2, b2, w3, s3, b3,
                                         ws_newxyz, ws_nnidx, ws_nnkey, ws_FL);
    fuse_kernel<<<2048, 256, 0, stream>>>(pts_cam, FI, tw1, tb1, tw2, tb2, tw3, tb3,
                                          gw_raw, gb_raw, gw_img, gb_img, gw_lid, gb_lid,
                                          uw, ub, vw, vb, ws_idx, ws_newxyz, ws_FL, out);
}

// Round 12
// 6380.145 us; speedup vs baseline: 1.4305x; 1.4305x over previous
//
#include <hip/hip_runtime.h>
#include <math.h>
#include <float.h>

#define BN   2
#define NPTS 16384
#define MPTS 4096
#define KGN  32
#define CIN  64
#define CLN  64

// ---------- exact fp32 helpers (no FMA contraction; must match np fp32) ----------
__device__ __forceinline__ float exadd(float a, float b) {
#pragma clang fp contract(off)
    float r = a + b; return r;
}
__device__ __forceinline__ float exsub(float a, float b) {
#pragma clang fp contract(off)
    float r = a - b; return r;
}
__device__ __forceinline__ float exmul(float a, float b) {
#pragma clang fp contract(off)
    float r = a * b; return r;
}

__device__ __forceinline__ float wave_sum64(float v) {
#pragma unroll
    for (int off = 1; off < 64; off <<= 1) v += __shfl_xor(v, off);
    return v;
}

// =====================================================================
// K0: pack points as float4(x, y, z, ||p||^2) once. sb order matches
// jnp.sum(b*b,-1): ((x*x + y*y) + z*z), contract off. Values verbatim.
// =====================================================================
__global__ __launch_bounds__(256) void prep_kernel(const float* __restrict__ xyz,
                                                   float4* __restrict__ pts4) {
    const int i = blockIdx.x * 256 + threadIdx.x;   // 0 .. BN*NPTS-1
    const float x = xyz[3 * i + 0];
    const float y = xyz[3 * i + 1];
    const float z = xyz[3 * i + 2];
    const float sb = exadd(exadd(exmul(x, x), exmul(y, y)), exmul(z, z));
    pts4[i] = make_float4(x, y, z, sb);
}

// =====================================================================
// K1: FPS — FINAL (R7 structure, best measured: fps 6000us, total 6377).
// Eleven-round summary: this exact structure is the empirical optimum.
//   * R10 (packed f32x2 update): VALUBusy 84->57% but TIME FLAT =>
//     VALU issue is NOT binding.
//   * R11 (LDS coord broadcast replacing s_load): regressed =>
//     centroid-load latency is NOT binding in isolation.
//   * R3/R5 (single-barrier / u64-atomic plumbing): heavy regressions.
//   * R5 (512x32 strided), R9 (LDS-staged coords): neutral-to-worse.
//   * FETCH_SIZE is KB (~262KB = input-sized): no scratch stream.
// The kernel is latency-bound on a sequential 4096-iteration loop
// occupying 2/256 CUs; per-iteration ~3500 cyc is a scheduler
// equilibrium of {update issue, 6-step wave reduce, B1, block reduce,
// scan+atomicMin, B2, swidx read, s_load centroid} that resisted all
// mechanistic levers. Cross-CU splits fail on sync arithmetic
// (~800-3000 cyc/iter cross-XCD >> halved update work).
// Value chain (verbatim-equivalent to the passing reference):
//   d = (dx*dx + dy*dy) + dz*dz  (fp32, no contraction),
//   dist = fminf(dist, d), init 1e10, start index 0,
//   argmax tie-break = first occurrence (smallest global index).
// Ownership: thread t owns gidx = t*16 + i (contiguous). Tie-break:
// scan checks i=15 first / i=0 LAST (last assignment wins) -> smallest
// matching i; across threads atomicMin on explicit global indices.
// bm is bit-exact (fmaxf tree returns one of its inputs; dists >= +0,
// no NaN). swidx ping-pong reset ordering: reset of slot (m+1)&1 sits
// between B1(m) and B2(m); readers finished before B1(m); next writers
// start after B1(m+1) > B2(m) > reset. No race.
// =====================================================================
__global__ __launch_bounds__(1024, 4) void fps_kernel(const float4* __restrict__ P4,
                                                      int* __restrict__ out_idx) {
    const int b = blockIdx.x;
    const int t = threadIdx.x;
    const float4* P = P4 + (size_t)b * NPTS;

    // ---- load 16 points into NAMED scalars, then pin each once ----
#define FPS_LOAD(i) float4 a##i = P[t * 16 + i];
    FPS_LOAD(0)  FPS_LOAD(1)  FPS_LOAD(2)  FPS_LOAD(3)
    FPS_LOAD(4)  FPS_LOAD(5)  FPS_LOAD(6)  FPS_LOAD(7)
    FPS_LOAD(8)  FPS_LOAD(9)  FPS_LOAD(10) FPS_LOAD(11)
    FPS_LOAD(12) FPS_LOAD(13) FPS_LOAD(14) FPS_LOAD(15)
#undef FPS_LOAD

#define FPS_PIN(i) \
    float px##i = a##i.x, py##i = a##i.y, pz##i = a##i.z, dd##i = 1e10f; \
    asm volatile("" : "+v"(px##i), "+v"(py##i), "+v"(pz##i));
    FPS_PIN(0)  FPS_PIN(1)  FPS_PIN(2)  FPS_PIN(3)
    FPS_PIN(4)  FPS_PIN(5)  FPS_PIN(6)  FPS_PIN(7)
    FPS_PIN(8)  FPS_PIN(9)  FPS_PIN(10) FPS_PIN(11)
    FPS_PIN(12) FPS_PIN(13) FPS_PIN(14) FPS_PIN(15)
#undef FPS_PIN

    __shared__ float smax[16];
    __shared__ int   swidx[2];

    if (t == 0) { swidx[0] = 0x7FFFFFFF; swidx[1] = 0x7FFFFFFF; }
    __syncthreads();

    int cidx = 0;   // current centroid index == out_idx[m] (reference: far starts at 0)

    for (int m = 0; m < MPTS; ++m) {
        if (t == 0) out_idx[b * MPTS + m] = cidx;   // fire-and-forget store

        // scalar broadcast load of the centroid (uniform address -> s_load)
        const int ci = __builtin_amdgcn_readfirstlane(cidx);
        const float4 C = P[ci];
        const float cx = C.x, cy = C.y, cz = C.z;

        float lmax = -1.0f;
#define FPS_UPD(i) { \
        float dx = exsub(px##i, cx); \
        float dy = exsub(py##i, cy); \
        float dz = exsub(pz##i, cz); \
        float d  = exadd(exadd(exmul(dx, dx), exmul(dy, dy)), exmul(dz, dz)); \
        dd##i = fminf(dd##i, d); \
        lmax = fmaxf(lmax, dd##i); }
        FPS_UPD(0)  FPS_UPD(1)  FPS_UPD(2)  FPS_UPD(3)
        FPS_UPD(4)  FPS_UPD(5)  FPS_UPD(6)  FPS_UPD(7)
        FPS_UPD(8)  FPS_UPD(9)  FPS_UPD(10) FPS_UPD(11)
        FPS_UPD(12) FPS_UPD(13) FPS_UPD(14) FPS_UPD(15)
#undef FPS_UPD

        // wave-level f32 max
        float wmax = lmax;
#pragma unroll
        for (int off = 1; off < 64; off <<= 1) wmax = fmaxf(wmax, __shfl_xor(wmax, off));
        if ((t & 63) == 0) smax[t >> 6] = wmax;

        __syncthreads();                               // B1

        // reset the slot used NEXT iteration (ordering: see header proof)
        if (t == 0) swidx[(m + 1) & 1] = 0x7FFFFFFF;

        // block max — replicated parallel reduce, every thread ends with bm
        float bm = smax[t & 15];
#pragma unroll
        for (int off = 1; off < 16; off <<= 1) bm = fmaxf(bm, __shfl_xor(bm, off));

        // candidates publish min global index (exact first-index tie-break)
        if (lmax == bm) {
            int sel = 0;
            // i=15 checked FIRST, i=0 LAST -> last assignment wins -> smallest i
#define FPS_SCAN(i) if (dd##i == bm) sel = i;
            FPS_SCAN(15) FPS_SCAN(14) FPS_SCAN(13) FPS_SCAN(12)
            FPS_SCAN(11) FPS_SCAN(10) FPS_SCAN(9)  FPS_SCAN(8)
            FPS_SCAN(7)  FPS_SCAN(6)  FPS_SCAN(5)  FPS_SCAN(4)
            FPS_SCAN(3)  FPS_SCAN(2)  FPS_SCAN(1)  FPS_SCAN(0)
#undef FPS_SCAN
            atomicMin(&swidx[m & 1], t * 16 + sel);
        }

        __syncthreads();                               // B2
        cidx = swidx[m & 1];
    }
}

// =====================================================================
// K2: exact 32-NN, wave per centroid, NO per-lane arrays.
// Wave-wide sorted top-32 lives in ONE (key,idx) register pair per
// lane (lanes 0..31, ascending (key,idx) lex). Candidates found via
// ballot; each inserted exactly: p = popc(ballot(lex-less)), shift
// lanes >= p up by one, lane p takes the candidate.
// Exactness: selection by (key,idx) lex = lax.top_k stable set; insert
// order irrelevant (final content = top-32 of union). Keys use the
// exact chain: d2 = (sa+sb) - 2*dot, key = fmaxf(d2,0).
// Radius pre-filter sqrtf(dk)<=0.8f is set-equivalent: the radius set
// is down-closed in key order, so top32(all) ∩ radius == top32(radius).
// Sentinels (FLT_MAX, idx 0) fail the mask in mlp; idx 0 safe gather.
// =====================================================================
__global__ __launch_bounds__(256) void knn_kernel(const float4* __restrict__ pts4,
                                                  const int* __restrict__ fps_idx,
                                                  float* __restrict__ newxyz,
                                                  int* __restrict__ nn_idx,
                                                  float* __restrict__ nn_key) {
    const int lane = threadIdx.x & 63;
    const int g    = blockIdx.x * 4 + (threadIdx.x >> 6);   // centroid 0..8191
    const int b    = g >> 12;
    const float4* P = pts4 + (size_t)b * NPTS;

    const int far = fps_idx[g];
    const float4 C = P[far];
    if (lane == 0) {
        newxyz[g * 3 + 0] = C.x;
        newxyz[g * 3 + 1] = C.y;
        newxyz[g * 3 + 2] = C.z;
    }
    const float sa = C.w;

    float skey = FLT_MAX;   // lanes 0..31: sorted entries; lanes 32..63: inert
    int   sidx = 0;

    for (int it = 0; it < NPTS / 64; ++it) {
        const int j = it * 64 + lane;
        const float4 Q = P[j];
        const float dot = exadd(exadd(exmul(C.x, Q.x), exmul(C.y, Q.y)), exmul(C.z, Q.z));
        const float d2  = exsub(exadd(sa, Q.w), exadd(dot, dot));
        const float dk  = fmaxf(d2, 0.0f);
        // current 32nd-best (tau) from lane 31 — stale within the iteration is
        // fine: the insert itself recomputes the exact position.
        const float tk = __shfl(skey, 31);
        const int   ti = __shfl(sidx, 31);
        const bool pass = (sqrtf(dk) <= 0.8f) &&
                          ((dk < tk) || (dk == tk && j < ti));
        unsigned long long mask = __ballot(pass);
        while (mask) {
            const int src = __ffsll(mask) - 1;
            mask &= mask - 1;
            const float ck = __shfl(dk, src);
            const int   cj = it * 64 + src;
            const bool less = (skey < ck) || (skey == ck && sidx < cj);
            const int p = __popcll(__ballot(less));   // wave-uniform rank
            if (p < 32) {                              // wave-uniform branch
                const float upk = __shfl_up(skey, 1);
                const int   upi = __shfl_up(sidx, 1);
                if (lane < 32) {
                    if (lane == p)     { skey = ck;  sidx = cj; }
                    else if (lane > p) { skey = upk; sidx = upi; }
                }
            }
        }
    }
    if (lane < KGN) {
        nn_idx[(size_t)g * KGN + lane] = sidx;
        nn_key[(size_t)g * KGN + lane] = skey;
    }
}

// =====================================================================
// K3: shared MLP 3->32->32->64 (+BN affine +ReLU), radius mask via
// sqrtf(nn_key) <= 0.8, max over 32 neighbors.
// =====================================================================
__global__ __attribute__((amdgpu_waves_per_eu(4, 4)))
__launch_bounds__(256) void mlp_kernel(const float* __restrict__ xyz,
                                       const float* __restrict__ w1, const float* __restrict__ s1, const float* __restrict__ b1,
                                       const float* __restrict__ w2, const float* __restrict__ s2, const float* __restrict__ b2,
                                       const float* __restrict__ w3, const float* __restrict__ s3, const float* __restrict__ b3,
                                       const float* __restrict__ newxyz,
                                       const int* __restrict__ nn_idx,
                                       const float* __restrict__ nn_key,
                                       float* __restrict__ FLout) {
    __shared__ float W1[96], S1[32], B1[32];
    __shared__ float W2[1024], S2[32], B2[32];
    __shared__ float W3[2048], S3[64], B3[64];
    const int tid = threadIdx.x;
    for (int i = tid; i < 96; i += 256)   W1[i] = w1[i];
    for (int i = tid; i < 32; i += 256) { S1[i] = s1[i]; B1[i] = b1[i]; S2[i] = s2[i]; B2[i] = b2[i]; }
    for (int i = tid; i < 1024; i += 256) W2[i] = w2[i];
    for (int i = tid; i < 2048; i += 256) W3[i] = w3[i];
    for (int i = tid; i < 64; i += 256) { S3[i] = s3[i]; B3[i] = b3[i]; }
    __syncthreads();

    const int n  = tid & 31;
    const int g  = blockIdx.x * 8 + (tid >> 5);   // centroid 0..8191
    const int b  = g >> 12;
    const size_t base = (size_t)g * KGN + n;
    const int   nj = nn_idx[base];
    const float nk = nn_key[base];

    const float* X = xyz + (size_t)b * NPTS * 3;
    const float gx = X[nj * 3 + 0] - newxyz[g * 3 + 0];
    const float gy = X[nj * 3 + 1] - newxyz[g * 3 + 1];
    const float gz = X[nj * 3 + 2] - newxyz[g * 3 + 2];

    float h1[32];
#pragma unroll
    for (int o = 0; o < 32; ++o) {
        float a = gx * W1[o * 3 + 0] + gy * W1[o * 3 + 1] + gz * W1[o * 3 + 2];
        h1[o] = fmaxf(a * S1[o] + B1[o], 0.0f);
    }
    float h2[32];
#pragma unroll
    for (int o = 0; o < 32; ++o) {
        float a = 0.0f;
#pragma unroll
        for (int k = 0; k < 32; ++k) a += h1[k] * W2[o * 32 + k];
        h2[o] = fmaxf(a * S2[o] + B2[o], 0.0f);
    }
    const bool valid = (sqrtf(nk) <= 0.8f);   // exact mask (sentinel FLT_MAX -> false)

    for (int o = 0; o < 64; ++o) {
        float a = 0.0f;
#pragma unroll
        for (int k = 0; k < 32; ++k) a += h2[k] * W3[o * 32 + k];
        float v = fmaxf(a * S3[o] + B3[o], 0.0f);
        v = valid ? v : -INFINITY;
#pragma unroll
        for (int off = 1; off < 32; off <<= 1) v = fmaxf(v, __shfl_xor(v, off));
        if (n == (o & 31)) FLout[(size_t)g * CLN + o] = v;
    }
}

// =====================================================================
// K4: DAM fusion. Wave per centroid, lane = channel.
// LDS-transposed 64x64 weights for conflict-free per-lane reads.
// =====================================================================
__global__ __launch_bounds__(256) void fuse_kernel(const float* __restrict__ pts_cam,
                                                   const float* __restrict__ FIn,
                                                   const float* __restrict__ tw1, const float* __restrict__ tb1,
                                                   const float* __restrict__ tw2, const float* __restrict__ tb2,
                                                   const float* __restrict__ tw3, const float* __restrict__ tb3,
                                                   const float* __restrict__ gw_raw, const float* __restrict__ gb_raw,
                                                   const float* __restrict__ gw_img, const float* __restrict__ gb_img,
                                                   const float* __restrict__ gw_lid, const float* __restrict__ gb_lid,
                                                   const float* __restrict__ uw, const float* __restrict__ ub,
                                                   const float* __restrict__ vw, const float* __restrict__ vb,
                                                   const int* __restrict__ fps_idx,
                                                   const float* __restrict__ newxyz,
                                                   const float* __restrict__ FLin,
                                                   float* __restrict__ out) {
    __shared__ float WIm[4096], WLi[4096], WT2[4096];
    const int tid = threadIdx.x;
    for (int i = tid; i < 4096; i += 256) {
        int c = i >> 6, k = i & 63;          // weight[c][k] -> transposed [k][c]
        WIm[k * 64 + c] = gw_img[i];
        WLi[k * 64 + c] = gw_lid[i];
        WT2[k * 64 + c] = tw2[i];
    }
    __syncthreads();

    const int lane = tid & 63;
    const int g    = blockIdx.x * 4 + (tid >> 6);   // centroid 0..8191
    const int b    = g >> 12;
    const int m    = g & (MPTS - 1);
    const int far  = fps_idx[g];

    const float fi_in = FIn[((size_t)(b * CIN + lane)) * NPTS + far];
    const float fl_in = FLin[(size_t)g * CLN + lane];
    const float nx = newxyz[g * 3 + 0], ny = newxyz[g * 3 + 1], nz = newxyz[g * 3 + 2];

    float fr = fmaxf(nx * gw_raw[lane * 3 + 0] + ny * gw_raw[lane * 3 + 1] +
                     nz * gw_raw[lane * 3 + 2] + gb_raw[lane], 0.0f);

    float ai = gb_img[lane], al = gb_lid[lane];
#pragma unroll 8
    for (int k = 0; k < 64; ++k) {
        float vi = __shfl(fi_in, k);
        float vl = __shfl(fl_in, k);
        ai += vi * WIm[k * 64 + lane];
        al += vl * WLi[k * 64 + lane];
    }
    const float s = tanhf(fr + fmaxf(ai, 0.0f) + fmaxf(al, 0.0f));

    // AdaptiveThresholdNet on constant density
    const float dens = (float)(64.0 / (4.0 / 3.0 * 3.14159 * 1.0));
    float t1 = fmaxf(dens * tw1[lane] + tb1[lane], 0.0f);
    float a2 = tb2[lane];
#pragma unroll 8
    for (int k = 0; k < 64; ++k) a2 += __shfl(t1, k) * WT2[k * 64 + lane];
    float t2 = fmaxf(a2, 0.0f);
    float a3 = wave_sum64(t2 * tw3[lane]) + tb3[0];
    float thr = 20.0f + 40.0f * (1.0f / (1.0f + expf(-a3)));

    float aI = wave_sum64(s * uw[lane]) + ub[0];
    float aL = wave_sum64(s * vw[lane]) + vb[0];
    float wIv = 1.0f / (1.0f + expf(-aI));
    float wLv = 1.0f / (1.0f + expf(-aL));

    const float z = pts_cam[((size_t)b * NPTS + far) * 3 + 2];
    const bool near = (z <= thr);

    const size_t o1 = ((size_t)(b * 128 + lane)) * MPTS + m;
    out[o1]                       = near ? fl_in        : fi_in;
    out[o1 + (size_t)64 * MPTS]   = near ? fi_in * wIv  : fl_in * wLv;
}

// =====================================================================
extern "C" void kernel_launch(void* const* d_in, const int* in_sizes, int n_in,
                              void* d_out, int out_size, void* d_ws, size_t ws_size,
                              hipStream_t stream) {
    const float* xyz     = (const float*)d_in[0];
    const float* pts_cam = (const float*)d_in[1];
    const float* FI      = (const float*)d_in[2];
    const float* w1 = (const float*)d_in[3];
    const float* s1 = (const float*)d_in[4];
    const float* b1 = (const float*)d_in[5];
    const float* w2 = (const float*)d_in[6];
    const float* s2 = (const float*)d_in[7];
    const float* b2 = (const float*)d_in[8];
    const float* w3 = (const float*)d_in[9];
    const float* s3 = (const float*)d_in[10];
    const float* b3 = (const float*)d_in[11];
    const float* tw1 = (const float*)d_in[12];
    const float* tb1 = (const float*)d_in[13];
    const float* tw2 = (const float*)d_in[14];
    const float* tb2 = (const float*)d_in[15];
    const float* tw3 = (const float*)d_in[16];
    const float* tb3 = (const float*)d_in[17];
    const float* gw_raw = (const float*)d_in[18];
    const float* gb_raw = (const float*)d_in[19];
    const float* gw_img = (const float*)d_in[20];
    const float* gb_img = (const float*)d_in[21];
    const float* gw_lid = (const float*)d_in[22];
    const float* gb_lid = (const float*)d_in[23];
    const float* uw = (const float*)d_in[24];
    const float* ub = (const float*)d_in[25];
    const float* vw = (const float*)d_in[26];
    const float* vb = (const float*)d_in[27];
    float* out = (float*)d_out;

    // workspace layout (bytes) — total 4,325,376.
    // pts4 is dead after knn; FL (written by mlp, later) aliases its region.
    char* ws = (char*)d_ws;
    int*    ws_idx    = (int*)   (ws + 0);         // 8192 ints    (32 KB)
    float*  ws_newxyz = (float*) (ws + 32768);     // 24576 f      (96 KB)  -> 131072
    float4* ws_pts4   = (float4*)(ws + 131072);    // 32768 float4 (512 KB) -> 655360 [dead after knn]
    float*  ws_FL     = (float*) (ws + 131072);    // 524288 f     (2 MB)   -> 2228224 [aliases pts4]
    int*    ws_nnidx  = (int*)   (ws + 2228224);   // 262144 ints  (1 MB)   -> 3276800
    float*  ws_nnkey  = (float*) (ws + 3276800);   // 262144 f     (1 MB)   -> 4325376
    (void)ws_size; (void)in_sizes; (void)n_in; (void)out_size;

    prep_kernel<<<(BN * NPTS) / 256, 256, 0, stream>>>(xyz, ws_pts4);
    fps_kernel<<<BN, 1024, 0, stream>>>(ws_pts4, ws_idx);
    knn_kernel<<<2048, 256, 0, stream>>>(ws_pts4, ws_idx, ws_newxyz, ws_nnidx, ws_nnkey);
    mlp_kernel<<<1024, 256, 0, stream>>>(xyz, w1, s1, b1, w2, s2, b2, w3, s3, b3,
                                         ws_newxyz, ws_nnidx, ws_nnkey, ws_FL);
    fuse_kernel<<<2048, 256, 0, stream>>>(pts_cam, FI, tw1, tb1, tw2, tb2, tw3, tb3,
                                          gw_raw, gb_raw, gw_img, gb_img, gw_lid, gb_lid,
                                          uw, ub, vw, vb, ws_idx, ws_newxyz, ws_FL, out);
}